// Round 13
// baseline (711.251 us; speedup 1.0000x reference)
//
#include <hip/hip_runtime.h>
#include <hip/hip_bf16.h>

#define N_NODES 80000
#define N_EDGES 1280000
constexpr int DN = 128;   // node input dim
constexpr int DE = 32;    // edge input dim
constexpr int H  = 64;    // hidden
constexpr int H2 = 128;   // 2*hidden
constexpr int CSTRIDE = 32;  // padded counter stride (128 B/line) to kill same-line atomic serialization
constexpr float EPS_GEN = 1e-7f;
constexpr float EPS_BN  = 1e-5f;

typedef _Float16 f16x8 __attribute__((ext_vector_type(8)));
typedef _Float16 f16x4 __attribute__((ext_vector_type(4)));
typedef float f32x4 __attribute__((ext_vector_type(4)));

__device__ __forceinline__ void atomAddF(float* p, float v) {
  __hip_atomic_fetch_add(p, v, __ATOMIC_RELAXED, __HIP_MEMORY_SCOPE_AGENT);
}

// ---------------- weight prep (all matrices) + cntPad zeroing, one dispatch ----------------
// frag-image: slab (n2*NK+kk) of 512 halves; elem ((kg*16+m16)*8+j) = W[kk*32+kg*8+j][n2*16+m16]
struct PrepDesc { const float* W; _Float16* img; int K; int OC; int blkStart; };
struct PrepAll { PrepDesc d[8]; float4* zero; int prepBlocks; size_t zeroN; };

__global__ void k_prep_all(PrepAll P) {
  int b = blockIdx.x;
  if (b >= P.prepBlocks) {   // zero cntPad region
    size_t i = (size_t)(b - P.prepBlocks) * 256 + threadIdx.x;
    if (i < P.zeroN) P.zero[i] = (float4){0.f, 0.f, 0.f, 0.f};
    return;
  }
  int i = 0;
#pragma unroll
  for (int t = 1; t < 8; ++t)
    if (P.d[t].blkStart <= b) i = t;
  const PrepDesc D = P.d[i];
  int idx = (b - D.blkStart) * 256 + threadIdx.x;
  if (idx >= D.K * D.OC) return;
  int nslabK = D.K >> 5;
  int j = idx & 7, m16 = (idx >> 3) & 15, kg = (idx >> 7) & 3;
  int slab = idx >> 9;
  int kk = slab % nslabK, n2 = slab / nslabK;
  int k = kk * 32 + kg * 8 + j, n = n2 * 16 + m16;
  D.img[idx] = (_Float16)D.W[k * D.OC + n];
}

// ---------------- generic dense MFMA: out[orow,:] = f(A[row,:]) @ W + b ----------------
// SCATOUT: orow = posmap[row]. STATS: accumulate col sums/sumsq (use with no OUT -> stats-only).
template <int K, int OC, bool IN16, bool BIAS,
          bool RELU_OUT, bool OUT16, bool OUT32, bool SCATOUT, bool STATS>
__global__ __launch_bounds__(256) void k_dense(
    const void* __restrict__ Ain, const _Float16* __restrict__ wimg,
    const float* __restrict__ bias,
    const int* __restrict__ posmap,
    _Float16* __restrict__ out16, float* __restrict__ out32,
    float* __restrict__ sums_out) {
  constexpr int NK = K / 32, NF = OC / 16;
  __shared__ float sStat[STATS ? 1024 : 1];   // [2][4 waves][128]
  const int tid = threadIdx.x, wv = tid >> 6, lane = tid & 63;
  const int m16 = lane & 15, kg = lane >> 4;
  const int rowbase = blockIdx.x * 64 + wv * 16;
  const int arow = rowbase + m16;
  f32x4 acc[NF];
#pragma unroll
  for (int n2 = 0; n2 < NF; ++n2) {
    float bv = BIAS ? bias[n2 * 16 + m16] : 0.0f;
    acc[n2] = (f32x4){bv, bv, bv, bv};
  }
  const _Float16* wp = wimg + (size_t)lane * 8;
#pragma unroll
  for (int kk = 0; kk < NK; ++kk) {
    f16x8 a;
    if constexpr (IN16) {
      const _Float16* ap = (const _Float16*)Ain + (size_t)arow * K + kg * 8 + kk * 32;
      a = *(const f16x8*)ap;
    } else {
      const float* ap = (const float*)Ain + (size_t)arow * K + kg * 8 + kk * 32;
      float4 v0 = *(const float4*)ap;
      float4 v1 = *(const float4*)(ap + 4);
      a = (f16x8){(_Float16)v0.x, (_Float16)v0.y, (_Float16)v0.z, (_Float16)v0.w,
                  (_Float16)v1.x, (_Float16)v1.y, (_Float16)v1.z, (_Float16)v1.w};
    }
#pragma unroll
    for (int n2 = 0; n2 < NF; ++n2) {
      f16x8 bb = *(const f16x8*)(wp + ((size_t)(n2 * NK + kk) << 9));
      acc[n2] = __builtin_amdgcn_mfma_f32_16x16x32_f16(a, bb, acc[n2], 0, 0, 0);
    }
  }
  if constexpr (OUT16 || OUT32) {
#pragma unroll
    for (int n2 = 0; n2 < NF; ++n2)
#pragma unroll
      for (int r = 0; r < 4; ++r) {
        float o = acc[n2][r];
        if constexpr (RELU_OUT) o = fmaxf(o, 0.0f);
        int orow = rowbase + kg * 4 + r;
        if constexpr (SCATOUT) orow = posmap[orow];
        size_t oi = (size_t)orow * OC + n2 * 16 + m16;
        if constexpr (OUT16) out16[oi] = (_Float16)o;
        if constexpr (OUT32) out32[oi] = o;
      }
  }
  if constexpr (STATS) {
    static_assert(!STATS || NF == 8, "STATS assumes OC==128");
#pragma unroll
    for (int n2 = 0; n2 < NF; ++n2) {
      float s = acc[n2][0] + acc[n2][1] + acc[n2][2] + acc[n2][3];
      float q = acc[n2][0] * acc[n2][0] + acc[n2][1] * acc[n2][1] +
                acc[n2][2] * acc[n2][2] + acc[n2][3] * acc[n2][3];
      s += __shfl_xor(s, 16); s += __shfl_xor(s, 32);
      q += __shfl_xor(q, 16); q += __shfl_xor(q, 32);
      if (kg == 0) {
        sStat[wv * 128 + n2 * 16 + m16] = s;
        sStat[512 + wv * 128 + n2 * 16 + m16] = q;
      }
    }
    __syncthreads();
    {
      int which = tid >> 7, f = tid & 127;
      const float* b0 = sStat + which * 512;
      float v = b0[f] + b0[128 + f] + b0[256 + f] + b0[384 + f];
      atomAddF(&sums_out[which * H2 + f], v);
    }
  }
}

// ---------------- fused BN-MLP: out = relu( relu(bn(hsum@W1)) @ W2 ) ----------------
template <bool OUT32>
__global__ __launch_bounds__(256) void k_mlp2f(
    const _Float16* __restrict__ hsum, const _Float16* __restrict__ w1img,
    const _Float16* __restrict__ w2img, const float* __restrict__ sums,
    const float* __restrict__ g, const float* __restrict__ be,
    _Float16* __restrict__ out16, float* __restrict__ out32) {
  constexpr int TP = 136;                 // LDS tile pitch (halves)
  __shared__ float sSC[H2], sSH[H2];
  __shared__ _Float16 sT[64 * TP];        // 17408 B
  const int tid = threadIdx.x, wv = tid >> 6, lane = tid & 63;
  const int m16 = lane & 15, kg = lane >> 4;
  const int rowbase = blockIdx.x * 64 + wv * 16;

  for (int i = tid; i < H2; i += 256) {
    float mu  = sums[i] * (1.0f / N_NODES);
    float var = sums[H2 + i] * (1.0f / N_NODES) - mu * mu;
    float sc  = rsqrtf(var + EPS_BN) * g[i];
    sSC[i] = sc;
    sSH[i] = be[i] - mu * sc;
  }

  // phase 1: h3 = hsum @ W1 (K=64 -> NK=2, OC=128 -> NF=8)
  f32x4 acc1[8];
#pragma unroll
  for (int n2 = 0; n2 < 8; ++n2) acc1[n2] = (f32x4){0.f, 0.f, 0.f, 0.f};
  const _Float16* wp1 = w1img + (size_t)lane * 8;
#pragma unroll
  for (int kk = 0; kk < 2; ++kk) {
    f16x8 a = *(const f16x8*)(hsum + (size_t)(rowbase + m16) * H + kg * 8 + kk * 32);
#pragma unroll
    for (int n2 = 0; n2 < 8; ++n2) {
      f16x8 bb = *(const f16x8*)(wp1 + ((size_t)(n2 * 2 + kk) << 9));
      acc1[n2] = __builtin_amdgcn_mfma_f32_16x16x32_f16(a, bb, acc1[n2], 0, 0, 0);
    }
  }
  __syncthreads();   // sSC/sSH ready
  // phase 2: BN affine + relu on D-layout, write LDS transpose tile
#pragma unroll
  for (int n2 = 0; n2 < 8; ++n2) {
    int col = n2 * 16 + m16;
    float sc = sSC[col], sh = sSH[col];
#pragma unroll
    for (int r = 0; r < 4; ++r) {
      float v = fmaxf(fmaf(acc1[n2][r], sc, sh), 0.0f);
      sT[(wv * 16 + kg * 4 + r) * TP + col] = (_Float16)v;
    }
  }
  __syncthreads();
  // phase 3: out = sT @ W2 (K=128 -> NK=4, OC=64 -> NF=4)
  f32x4 acc2[4];
#pragma unroll
  for (int n2 = 0; n2 < 4; ++n2) acc2[n2] = (f32x4){0.f, 0.f, 0.f, 0.f};
  const _Float16* wp2 = w2img + (size_t)lane * 8;
#pragma unroll
  for (int kk = 0; kk < 4; ++kk) {
    f16x8 a2 = *(const f16x8*)&sT[(wv * 16 + m16) * TP + kg * 8 + kk * 32];
#pragma unroll
    for (int n2 = 0; n2 < 4; ++n2) {
      f16x8 bb = *(const f16x8*)(wp2 + ((size_t)(n2 * 4 + kk) << 9));
      acc2[n2] = __builtin_amdgcn_mfma_f32_16x16x32_f16(a2, bb, acc2[n2], 0, 0, 0);
    }
  }
#pragma unroll
  for (int n2 = 0; n2 < 4; ++n2)
#pragma unroll
    for (int r = 0; r < 4; ++r) {
      float o = fmaxf(acc2[n2][r], 0.0f);
      size_t oi = (size_t)(rowbase + kg * 4 + r) * H + n2 * 16 + m16;
      out16[oi] = (_Float16)o;
      if constexpr (OUT32) out32[oi] = o;
    }
}

// ---------------- edge update on sorted positions: T tiles/block ----------------
template <int OC, typename OUT_T, int T, bool SCAT>
__global__ __launch_bounds__(256) void k_edge_upd_srt(
    const _Float16* __restrict__ h, const _Float16* __restrict__ ea,
    const int4* __restrict__ eidsQ,
    const _Float16* __restrict__ wimg, const float* __restrict__ lb,
    OUT_T* __restrict__ eout) {
  constexpr int NF = OC / 16;
  __shared__ _Float16 sWf[NF * 6 * 512];
  __shared__ int sS[T * 64], sD[T * 64];
  __shared__ int sE[SCAT ? T * 64 : 1];
  const int tid = threadIdx.x, wv = tid >> 6, lane = tid & 63;
  const int m16 = lane & 15, kg = lane >> 4;
  const int p0 = blockIdx.x * (T * 64);

  for (int i = tid; i < T * 64; i += 256) {
    int4 t = eidsQ[p0 + i];
    sS[i] = t.y;
    sD[i] = t.z;
    if constexpr (SCAT) sE[i] = t.x;
  }
  {  // stage weights: linear copy (frag-ordered)
    const float4* s4 = (const float4*)wimg;
    float4* d4 = (float4*)sWf;
    constexpr int NV = NF * 6 * 512 / 8;
    for (int i = tid; i < NV; i += 256) d4[i] = s4[i];
  }
  __syncthreads();
  const _Float16* wp = sWf + (size_t)lane * 8;

  float bias_[NF];
#pragma unroll
  for (int n2 = 0; n2 < NF; ++n2) bias_[n2] = lb[n2 * 16 + m16];

  f16x8 FA[6], FB[6];
  auto LOADA = [&](f16x8* F, int l) {        // l = local row (pos - p0)
    const _Float16* a0 = h + (size_t)sS[l] * H + kg * 8;
    const _Float16* a1 = ea + (size_t)(p0 + l) * H + kg * 8;
    const _Float16* a2 = h + (size_t)sD[l] * H + kg * 8;
    F[0] = *(const f16x8*)a0;
    F[1] = *(const f16x8*)(a0 + 32);
    F[2] = *(const f16x8*)a1;
    F[3] = *(const f16x8*)(a1 + 32);
    F[4] = *(const f16x8*)a2;
    F[5] = *(const f16x8*)(a2 + 32);
  };
  auto COMPUTE = [&](const f16x8* F, int l) {
    f32x4 acc[NF];
#pragma unroll
    for (int n2 = 0; n2 < NF; ++n2)
      acc[n2] = (f32x4){bias_[n2], bias_[n2], bias_[n2], bias_[n2]};
#pragma unroll
    for (int kk = 0; kk < 6; ++kk)
#pragma unroll
      for (int n2 = 0; n2 < NF; ++n2) {
        f16x8 bb = *(const f16x8*)(wp + ((n2 * 6 + kk) << 9));
        acc[n2] = __builtin_amdgcn_mfma_f32_16x16x32_f16(F[kk], bb, acc[n2], 0, 0, 0);
      }
    const int lbase = l - m16;
#pragma unroll
    for (int n2 = 0; n2 < NF; ++n2)
#pragma unroll
      for (int r = 0; r < 4; ++r) {
        int lr = lbase + kg * 4 + r;
        int col = n2 * 16 + m16;
        if constexpr (SCAT)
          eout[(size_t)sE[lr] * OC + col] = (OUT_T)acc[n2][r];
        else
          eout[(size_t)(p0 + lr) * OC + col] = (OUT_T)acc[n2][r];
      }
  };

  const int l0 = wv * 16 + m16;
  LOADA(FA, l0);
  if (T > 1) LOADA(FB, l0 + 64);
#pragma unroll
  for (int t = 0; t < T; ++t) {
    if (t & 1) {
      COMPUTE(FB, l0 + t * 64);
      if (t + 2 < T) LOADA(FB, l0 + (t + 2) * 64);
    } else {
      COMPUTE(FA, l0 + t * 64);
      if (t + 2 < T) LOADA(FA, l0 + (t + 2) * 64);
    }
  }
}

// ---------------- CSR build: rank (padded atomics) -> scan -> pure scatter ----------------
__global__ void k_rank(const int* __restrict__ dst, int* cntPad, int* __restrict__ rank) {
  int e = blockIdx.x * blockDim.x + threadIdx.x;
  if (e < N_EDGES)
    rank[e] = atomicAdd(&cntPad[(size_t)dst[e] * CSTRIDE], 1);
}

__global__ void k_scan_blk(const int* __restrict__ cntPad, int* __restrict__ bsum) {
  __shared__ int sh[256];
  int i = blockIdx.x * 256 + threadIdx.x;
  sh[threadIdx.x] = (i < N_NODES) ? cntPad[(size_t)i * CSTRIDE] : 0;
  __syncthreads();
  for (int s = 128; s > 0; s >>= 1) {
    if (threadIdx.x < s) sh[threadIdx.x] += sh[threadIdx.x + s];
    __syncthreads();
  }
  if (threadIdx.x == 0) bsum[blockIdx.x] = sh[0];
}

__global__ void k_scan_top(int* bsum, int nb) {  // 1 block x 512, exclusive scan
  __shared__ int sh[512];
  int t = threadIdx.x;
  int orig = (t < nb) ? bsum[t] : 0;
  sh[t] = orig;
  __syncthreads();
  for (int off = 1; off < 512; off <<= 1) {
    int v = (t >= off) ? sh[t - off] : 0;
    __syncthreads();
    sh[t] += v;
    __syncthreads();
  }
  if (t < nb) bsum[t] = sh[t] - orig;
}

__global__ void k_scan_fin(const int* __restrict__ cntPad, const int* __restrict__ bsum,
                           int* __restrict__ start, int* __restrict__ cntC) {
  __shared__ int sh[256];
  int i = blockIdx.x * 256 + threadIdx.x;
  int t = threadIdx.x;
  int orig = (i < N_NODES) ? cntPad[(size_t)i * CSTRIDE] : 0;
  sh[t] = orig;
  __syncthreads();
  for (int off = 1; off < 256; off <<= 1) {
    int v = (t >= off) ? sh[t - off] : 0;
    __syncthreads();
    sh[t] += v;
    __syncthreads();
  }
  if (i < N_NODES) {
    start[i] = bsum[blockIdx.x] + sh[t] - orig;
    cntC[i] = orig;
  }
}

__global__ void k_scatter(const int* __restrict__ src, const int* __restrict__ dst,
                          const int* __restrict__ rank, const int* __restrict__ start,
                          int4* __restrict__ eidsQ, int* __restrict__ posOf) {
  int e = blockIdx.x * blockDim.x + threadIdx.x;
  if (e < N_EDGES) {
    int d = dst[e];
    int pos = start[d] + rank[e];
    eidsQ[pos] = make_int4(e, src[e], d, 0);   // single 16B scattered store, no atomics
    posOf[e] = pos;                             // coalesced
  }
}

// ---------------- CSR softmax-aggregation: wave/node, 16 edges parallel, CONTIGUOUS ea ----------------
// lane = (ep = lane&15) edge slot x (fg = lane>>4) 16-feature group; block 0 zeroes sums[256].
__global__ __launch_bounds__(256) void k_agg_csr(
    const _Float16* __restrict__ h, const _Float16* __restrict__ ea_s,
    const int4* __restrict__ eidsQ, const int* __restrict__ start,
    const int* __restrict__ cnt, _Float16* __restrict__ hsum,
    float* __restrict__ sums_clr) {
  if (blockIdx.x == 0) sums_clr[threadIdx.x] = 0.0f;
  const int lane = threadIdx.x & 63;
  const int wid  = (int)((blockIdx.x * blockDim.x + threadIdx.x) >> 6);
  if (wid >= N_NODES) return;
  const int ep = lane & 15, fg = lane >> 4;
  const int s0 = start[wid], c = cnt[wid];
  float num[16], den[16];
#pragma unroll
  for (int j = 0; j < 16; ++j) { num[j] = 0.0f; den[j] = 0.0f; }
  if (c > 0) {
    const int nit = (c + 15) >> 4;
    auto LD = [&](int i, f16x8& h0, f16x8& h1, f16x8& e0, f16x8& e1, bool& v) {
      int idx = min(i * 16 + ep, c - 1);
      int2 pe = *(const int2*)(eidsQ + s0 + idx);   // (e, src) prefix
      const _Float16* hp = h + (size_t)pe.y * H + fg * 16;
      const _Float16* eap = ea_s + (size_t)(s0 + idx) * H + fg * 16;
      h0 = *(const f16x8*)hp;  h1 = *(const f16x8*)(hp + 8);
      e0 = *(const f16x8*)eap; e1 = *(const f16x8*)(eap + 8);
      v = (i * 16 + ep < c);
    };
    f16x8 hA0, hA1, eA0, eA1, hB0, hB1, eB0, eB1;
    bool vA = false, vB = false;
    LD(0, hA0, hA1, eA0, eA1, vA);
    if (nit > 1) LD(1, hB0, hB1, eB0, eB1, vB);
    for (int i = 0; i < nit; ++i) {
      f16x8 h0 = hA0, h1 = hA1, e0 = eA0, e1 = eA1;
      bool vc = vA;
      hA0 = hB0; hA1 = hB1; eA0 = eB0; eA1 = eB1; vA = vB;
      if (i + 2 < nit) LD(i + 2, hB0, hB1, eB0, eB1, vB);
#pragma unroll
      for (int j = 0; j < 8; ++j) {
        float m0 = fmaxf((float)h0[j] + (float)e0[j], 0.0f) + EPS_GEN;
        float x0 = vc ? __expf(m0) : 0.0f;
        num[j] = fmaf(m0, x0, num[j]);
        den[j] += x0;
        float m1 = fmaxf((float)h1[j] + (float)e1[j], 0.0f) + EPS_GEN;
        float x1 = vc ? __expf(m1) : 0.0f;
        num[8 + j] = fmaf(m1, x1, num[8 + j]);
        den[8 + j] += x1;
      }
    }
  }
#pragma unroll
  for (int j = 0; j < 16; ++j) {
    num[j] += __shfl_xor(num[j], 1);
    num[j] += __shfl_xor(num[j], 2);
    num[j] += __shfl_xor(num[j], 4);
    num[j] += __shfl_xor(num[j], 8);
    den[j] += __shfl_xor(den[j], 1);
    den[j] += __shfl_xor(den[j], 2);
    den[j] += __shfl_xor(den[j], 4);
    den[j] += __shfl_xor(den[j], 8);
  }
  if (ep == 0) {
    const _Float16* hp = h + (size_t)wid * H + fg * 16;
    f16x8 hs0 = *(const f16x8*)hp, hs1 = *(const f16x8*)(hp + 8);
    f16x8 o0, o1;
#pragma unroll
    for (int j = 0; j < 8; ++j) {
      o0[j] = (_Float16)(num[j] / (den[j] + 1e-16f) + (float)hs0[j]);
      o1[j] = (_Float16)(num[8 + j] / (den[8 + j] + 1e-16f) + (float)hs1[j]);
    }
    _Float16* op = hsum + (size_t)wid * H + fg * 16;
    *(f16x8*)op = o0;
    *(f16x8*)(op + 8) = o1;
  }
}

extern "C" void kernel_launch(void* const* d_in, const int* in_sizes, int n_in,
                              void* d_out, int out_size, void* d_ws, size_t ws_size,
                              hipStream_t stream) {
  (void)in_sizes; (void)n_in; (void)out_size; (void)ws_size;
  const float* x      = (const float*)d_in[0];
  const int*   eidx   = (const int*)d_in[1];
  const float* eattr  = (const float*)d_in[2];
  const float* node_W = (const float*)d_in[3];
  const float* node_b = (const float*)d_in[4];
  const float* edge_W = (const float*)d_in[5];
  const float* edge_b = (const float*)d_in[6];
  const float* c1_W1  = (const float*)d_in[7];
  const float* c1_g   = (const float*)d_in[8];
  const float* c1_be  = (const float*)d_in[9];
  const float* c1_W2  = (const float*)d_in[10];
  const float* c2_W1  = (const float*)d_in[11];
  const float* c2_g   = (const float*)d_in[12];
  const float* c2_be  = (const float*)d_in[13];
  const float* c2_W2  = (const float*)d_in[14];
  const float* l1_W   = (const float*)d_in[15];
  const float* l1_b   = (const float*)d_in[16];
  const float* l2_W   = (const float*)d_in[17];
  const float* l2_b   = (const float*)d_in[18];

  const int* src = eidx;
  const int* dst = eidx + N_EDGES;

  char* wsb = (char*)d_ws;
  size_t off = 0;
  _Float16* ea_s  = (_Float16*)(wsb + off); off += (size_t)N_EDGES * H * 2;   // sorted-order ea
  _Float16* hA16  = (_Float16*)(wsb + off); off += (size_t)N_NODES * H * 2;
  _Float16* hB16  = (_Float16*)(wsb + off); off += (size_t)N_NODES * H * 2;
  _Float16* hC16  = (_Float16*)(wsb + off); off += (size_t)N_NODES * H * 2;
  _Float16* hsum16= (_Float16*)(wsb + off); off += (size_t)N_NODES * H * 2;
  float* sums     = (float*)(wsb + off);    off += 256 * 4;
  int* cntPad     = (int*)(wsb + off);      off += (size_t)N_NODES * CSTRIDE * 4;  // 10.24 MB
  int* startA     = (int*)(wsb + off);      off += (size_t)N_NODES * 4;
  int* cntC       = (int*)(wsb + off);      off += (size_t)N_NODES * 4;
  int* bsum       = (int*)(wsb + off);      off += 512 * 4;
  int* rankE      = (int*)(wsb + off);      off += (size_t)N_EDGES * 4;
  int4* eidsQ     = (int4*)(wsb + off);     off += (size_t)N_EDGES * 16;
  int* posOf      = (int*)(wsb + off);      off += (size_t)N_EDGES * 4;
  _Float16* wE    = (_Float16*)(wsb + off); off += DE * H * 2;
  _Float16* wN    = (_Float16*)(wsb + off); off += DN * H * 2;
  _Float16* w1a   = (_Float16*)(wsb + off); off += H * H2 * 2;
  _Float16* w1b   = (_Float16*)(wsb + off); off += H * H2 * 2;
  _Float16* w2a   = (_Float16*)(wsb + off); off += H2 * H * 2;
  _Float16* w2b   = (_Float16*)(wsb + off); off += H2 * H * 2;
  _Float16* wL1   = (_Float16*)(wsb + off); off += 3 * H * H * 2;
  _Float16* wL2   = (_Float16*)(wsb + off); off += 3 * H * 32 * 2;

  float* h_out  = (float*)d_out;                            // [N,64]
  float* ea_out = (float*)d_out + (size_t)N_NODES * H;      // [E,32]

  constexpr int NB = (N_NODES + 255) / 256;                 // 313 scan blocks

  // ---- one-time weight frag-images + cntPad zeroing (single dispatch) ----
  PrepAll P;
  P.d[0] = {edge_W, wE, DE, H, 0};       // 8 blocks
  P.d[1] = {node_W, wN, DN, H, 8};       // 32
  P.d[2] = {c1_W1, w1a, H, H2, 40};      // 32
  P.d[3] = {c2_W1, w1b, H, H2, 72};      // 32
  P.d[4] = {c1_W2, w2a, H2, H, 104};     // 32
  P.d[5] = {c2_W2, w2b, H2, H, 136};     // 32
  P.d[6] = {l1_W, wL1, 192, H, 168};     // 48
  P.d[7] = {l2_W, wL2, 192, 32, 216};    // 24 -> prep total 240
  P.zero = (float4*)cntPad;
  P.prepBlocks = 240;
  P.zeroN = (size_t)N_NODES * CSTRIDE / 4;   // 640000 float4s
  k_prep_all<<<240 + 2500, 256, 0, stream>>>(P);

  // ---- build CSR (padded-counter rank, atomic-free scatter) ----
  k_rank<<<(N_EDGES + 255) / 256, 256, 0, stream>>>(dst, cntPad, rankE);
  k_scan_blk<<<NB, 256, 0, stream>>>(cntPad, bsum);
  k_scan_top<<<1, 512, 0, stream>>>(bsum, NB);
  k_scan_fin<<<NB, 256, 0, stream>>>(cntPad, bsum, startA, cntC);
  k_scatter<<<(N_EDGES + 255) / 256, 256, 0, stream>>>(src, dst, rankE, startA, eidsQ, posOf);

  // ---- encoders (edge encoder: streaming read, scatter-write to sorted ea_s) ----
  k_dense<DE, H, false, true, false, true, false, true, false>
      <<<N_EDGES / 64, 256, 0, stream>>>(eattr, wE, edge_b,
                                         posOf, ea_s, nullptr, nullptr);
  k_dense<DN, H, false, true, false, true, false, false, false>
      <<<N_NODES / 64, 256, 0, stream>>>(x, wN, node_b,
                                         nullptr, hA16, nullptr, nullptr);

  // ---- conv layer 1 ----
  k_agg_csr<<<(N_NODES + 3) / 4, 256, 0, stream>>>(hA16, ea_s, eidsQ, startA, cntC, hsum16, sums);
  k_dense<H, H2, true, false, false, false, false, false, true>   // stats-only
      <<<N_NODES / 64, 256, 0, stream>>>(hsum16, w1a, nullptr,
                                         nullptr, nullptr, nullptr, sums);
  k_mlp2f<false><<<N_NODES / 64, 256, 0, stream>>>(hsum16, w1a, w2a, sums,
                                                   c1_g, c1_be, hB16, nullptr);
  k_edge_upd_srt<64, _Float16, 16, false>
      <<<N_EDGES / 1024, 256, 0, stream>>>(hB16, ea_s, eidsQ, wL1, l1_b, ea_s);  // in-place

  // ---- conv layer 2 ----
  k_agg_csr<<<(N_NODES + 3) / 4, 256, 0, stream>>>(hB16, ea_s, eidsQ, startA, cntC, hsum16, sums);
  k_dense<H, H2, true, false, false, false, false, false, true>   // stats-only
      <<<N_NODES / 64, 256, 0, stream>>>(hsum16, w1b, nullptr,
                                         nullptr, nullptr, nullptr, sums);
  k_mlp2f<true><<<N_NODES / 64, 256, 0, stream>>>(hsum16, w1b, w2b, sums,
                                                  c2_g, c2_be, hC16, h_out);
  k_edge_upd_srt<32, float, 16, true>
      <<<N_EDGES / 1024, 256, 0, stream>>>(hC16, ea_s, eidsQ, wL2, l2_b, ea_out);
}

// Round 14
// 590.355 us; speedup vs baseline: 1.2048x; 1.2048x over previous
//
#include <hip/hip_runtime.h>
#include <hip/hip_bf16.h>

#define N_NODES 80000
#define N_EDGES 1280000
constexpr int DN = 128;   // node input dim
constexpr int DE = 32;    // edge input dim
constexpr int H  = 64;    // hidden
constexpr int H2 = 128;   // 2*hidden
constexpr int CSTRIDE = 32;  // padded counter stride (128 B/line) to kill same-line atomic serialization
constexpr float EPS_GEN = 1e-7f;
constexpr float EPS_BN  = 1e-5f;

typedef _Float16 f16x8 __attribute__((ext_vector_type(8)));
typedef _Float16 f16x4 __attribute__((ext_vector_type(4)));
typedef float f32x4 __attribute__((ext_vector_type(4)));

__device__ __forceinline__ void atomAddF(float* p, float v) {
  __hip_atomic_fetch_add(p, v, __ATOMIC_RELAXED, __HIP_MEMORY_SCOPE_AGENT);
}

// ---------------- weight prep (all matrices) + cntPad zeroing, one dispatch ----------------
// frag-image: slab (n2*NK+kk) of 512 halves; elem ((kg*16+m16)*8+j) = W[kk*32+kg*8+j][n2*16+m16]
struct PrepDesc { const float* W; _Float16* img; int K; int OC; int blkStart; };
struct PrepAll { PrepDesc d[8]; float4* zero; int prepBlocks; size_t zeroN; };

__global__ void k_prep_all(PrepAll P) {
  int b = blockIdx.x;
  if (b >= P.prepBlocks) {   // zero cntPad region
    size_t i = (size_t)(b - P.prepBlocks) * 256 + threadIdx.x;
    if (i < P.zeroN) P.zero[i] = (float4){0.f, 0.f, 0.f, 0.f};
    return;
  }
  int i = 0;
#pragma unroll
  for (int t = 1; t < 8; ++t)
    if (P.d[t].blkStart <= b) i = t;
  const PrepDesc D = P.d[i];
  int idx = (b - D.blkStart) * 256 + threadIdx.x;
  if (idx >= D.K * D.OC) return;
  int nslabK = D.K >> 5;
  int j = idx & 7, m16 = (idx >> 3) & 15, kg = (idx >> 7) & 3;
  int slab = idx >> 9;
  int kk = slab % nslabK, n2 = slab / nslabK;
  int k = kk * 32 + kg * 8 + j, n = n2 * 16 + m16;
  D.img[idx] = (_Float16)D.W[k * D.OC + n];
}

// ---------------- generic dense MFMA: out[orow,:] = f(A[row,:]) @ W + b ----------------
// SCATOUT: orow = posmap[row]. STATS: accumulate col sums/sumsq (use with no OUT -> stats-only).
template <int K, int OC, bool IN16, bool BIAS,
          bool RELU_OUT, bool OUT16, bool OUT32, bool SCATOUT, bool STATS>
__global__ __launch_bounds__(256) void k_dense(
    const void* __restrict__ Ain, const _Float16* __restrict__ wimg,
    const float* __restrict__ bias,
    const int* __restrict__ posmap,
    _Float16* __restrict__ out16, float* __restrict__ out32,
    float* __restrict__ sums_out) {
  constexpr int NK = K / 32, NF = OC / 16;
  __shared__ float sStat[STATS ? 1024 : 1];   // [2][4 waves][128]
  const int tid = threadIdx.x, wv = tid >> 6, lane = tid & 63;
  const int m16 = lane & 15, kg = lane >> 4;
  const int rowbase = blockIdx.x * 64 + wv * 16;
  const int arow = rowbase + m16;
  f32x4 acc[NF];
#pragma unroll
  for (int n2 = 0; n2 < NF; ++n2) {
    float bv = BIAS ? bias[n2 * 16 + m16] : 0.0f;
    acc[n2] = (f32x4){bv, bv, bv, bv};
  }
  const _Float16* wp = wimg + (size_t)lane * 8;
#pragma unroll
  for (int kk = 0; kk < NK; ++kk) {
    f16x8 a;
    if constexpr (IN16) {
      const _Float16* ap = (const _Float16*)Ain + (size_t)arow * K + kg * 8 + kk * 32;
      a = *(const f16x8*)ap;
    } else {
      const float* ap = (const float*)Ain + (size_t)arow * K + kg * 8 + kk * 32;
      float4 v0 = *(const float4*)ap;
      float4 v1 = *(const float4*)(ap + 4);
      a = (f16x8){(_Float16)v0.x, (_Float16)v0.y, (_Float16)v0.z, (_Float16)v0.w,
                  (_Float16)v1.x, (_Float16)v1.y, (_Float16)v1.z, (_Float16)v1.w};
    }
#pragma unroll
    for (int n2 = 0; n2 < NF; ++n2) {
      f16x8 bb = *(const f16x8*)(wp + ((size_t)(n2 * NK + kk) << 9));
      acc[n2] = __builtin_amdgcn_mfma_f32_16x16x32_f16(a, bb, acc[n2], 0, 0, 0);
    }
  }
  if constexpr (OUT16 || OUT32) {
#pragma unroll
    for (int n2 = 0; n2 < NF; ++n2)
#pragma unroll
      for (int r = 0; r < 4; ++r) {
        float o = acc[n2][r];
        if constexpr (RELU_OUT) o = fmaxf(o, 0.0f);
        int orow = rowbase + kg * 4 + r;
        if constexpr (SCATOUT) orow = posmap[orow];
        size_t oi = (size_t)orow * OC + n2 * 16 + m16;
        if constexpr (OUT16) out16[oi] = (_Float16)o;
        if constexpr (OUT32) out32[oi] = o;
      }
  }
  if constexpr (STATS) {
    static_assert(!STATS || NF == 8, "STATS assumes OC==128");
#pragma unroll
    for (int n2 = 0; n2 < NF; ++n2) {
      float s = acc[n2][0] + acc[n2][1] + acc[n2][2] + acc[n2][3];
      float q = acc[n2][0] * acc[n2][0] + acc[n2][1] * acc[n2][1] +
                acc[n2][2] * acc[n2][2] + acc[n2][3] * acc[n2][3];
      s += __shfl_xor(s, 16); s += __shfl_xor(s, 32);
      q += __shfl_xor(q, 16); q += __shfl_xor(q, 32);
      if (kg == 0) {
        sStat[wv * 128 + n2 * 16 + m16] = s;
        sStat[512 + wv * 128 + n2 * 16 + m16] = q;
      }
    }
    __syncthreads();
    {
      int which = tid >> 7, f = tid & 127;
      const float* b0 = sStat + which * 512;
      float v = b0[f] + b0[128 + f] + b0[256 + f] + b0[384 + f];
      atomAddF(&sums_out[which * H2 + f], v);
    }
  }
}

// ---------------- fused BN-MLP: out = relu( relu(bn(hsum@W1)) @ W2 ) ----------------
template <bool OUT32>
__global__ __launch_bounds__(256) void k_mlp2f(
    const _Float16* __restrict__ hsum, const _Float16* __restrict__ w1img,
    const _Float16* __restrict__ w2img, const float* __restrict__ sums,
    const float* __restrict__ g, const float* __restrict__ be,
    _Float16* __restrict__ out16, float* __restrict__ out32) {
  constexpr int TP = 136;                 // LDS tile pitch (halves)
  __shared__ float sSC[H2], sSH[H2];
  __shared__ _Float16 sT[64 * TP];        // 17408 B
  const int tid = threadIdx.x, wv = tid >> 6, lane = tid & 63;
  const int m16 = lane & 15, kg = lane >> 4;
  const int rowbase = blockIdx.x * 64 + wv * 16;

  for (int i = tid; i < H2; i += 256) {
    float mu  = sums[i] * (1.0f / N_NODES);
    float var = sums[H2 + i] * (1.0f / N_NODES) - mu * mu;
    float sc  = rsqrtf(var + EPS_BN) * g[i];
    sSC[i] = sc;
    sSH[i] = be[i] - mu * sc;
  }

  // phase 1: h3 = hsum @ W1 (K=64 -> NK=2, OC=128 -> NF=8)
  f32x4 acc1[8];
#pragma unroll
  for (int n2 = 0; n2 < 8; ++n2) acc1[n2] = (f32x4){0.f, 0.f, 0.f, 0.f};
  const _Float16* wp1 = w1img + (size_t)lane * 8;
#pragma unroll
  for (int kk = 0; kk < 2; ++kk) {
    f16x8 a = *(const f16x8*)(hsum + (size_t)(rowbase + m16) * H + kg * 8 + kk * 32);
#pragma unroll
    for (int n2 = 0; n2 < 8; ++n2) {
      f16x8 bb = *(const f16x8*)(wp1 + ((size_t)(n2 * 2 + kk) << 9));
      acc1[n2] = __builtin_amdgcn_mfma_f32_16x16x32_f16(a, bb, acc1[n2], 0, 0, 0);
    }
  }
  __syncthreads();   // sSC/sSH ready
  // phase 2: BN affine + relu on D-layout, write LDS transpose tile
#pragma unroll
  for (int n2 = 0; n2 < 8; ++n2) {
    int col = n2 * 16 + m16;
    float sc = sSC[col], sh = sSH[col];
#pragma unroll
    for (int r = 0; r < 4; ++r) {
      float v = fmaxf(fmaf(acc1[n2][r], sc, sh), 0.0f);
      sT[(wv * 16 + kg * 4 + r) * TP + col] = (_Float16)v;
    }
  }
  __syncthreads();
  // phase 3: out = sT @ W2 (K=128 -> NK=4, OC=64 -> NF=4)
  f32x4 acc2[4];
#pragma unroll
  for (int n2 = 0; n2 < 4; ++n2) acc2[n2] = (f32x4){0.f, 0.f, 0.f, 0.f};
  const _Float16* wp2 = w2img + (size_t)lane * 8;
#pragma unroll
  for (int kk = 0; kk < 4; ++kk) {
    f16x8 a2 = *(const f16x8*)&sT[(wv * 16 + m16) * TP + kg * 8 + kk * 32];
#pragma unroll
    for (int n2 = 0; n2 < 4; ++n2) {
      f16x8 bb = *(const f16x8*)(wp2 + ((size_t)(n2 * 4 + kk) << 9));
      acc2[n2] = __builtin_amdgcn_mfma_f32_16x16x32_f16(a2, bb, acc2[n2], 0, 0, 0);
    }
  }
#pragma unroll
  for (int n2 = 0; n2 < 4; ++n2)
#pragma unroll
    for (int r = 0; r < 4; ++r) {
      float o = fmaxf(acc2[n2][r], 0.0f);
      size_t oi = (size_t)(rowbase + kg * 4 + r) * H + n2 * 16 + m16;
      out16[oi] = (_Float16)o;
      if constexpr (OUT32) out32[oi] = o;
    }
}

// ---------------- edge update on sorted positions: T tiles/block ----------------
template <int OC, typename OUT_T, int T, bool SCAT>
__global__ __launch_bounds__(256) void k_edge_upd_srt(
    const _Float16* __restrict__ h, const _Float16* __restrict__ ea,
    const int4* __restrict__ eidsQ,
    const _Float16* __restrict__ wimg, const float* __restrict__ lb,
    OUT_T* __restrict__ eout) {
  constexpr int NF = OC / 16;
  __shared__ _Float16 sWf[NF * 6 * 512];
  __shared__ int sS[T * 64], sD[T * 64];
  __shared__ int sE[SCAT ? T * 64 : 1];
  const int tid = threadIdx.x, wv = tid >> 6, lane = tid & 63;
  const int m16 = lane & 15, kg = lane >> 4;
  const int p0 = blockIdx.x * (T * 64);

  for (int i = tid; i < T * 64; i += 256) {
    int4 t = eidsQ[p0 + i];
    sS[i] = t.y;
    sD[i] = t.z;
    if constexpr (SCAT) sE[i] = t.x;
  }
  {  // stage weights: linear copy (frag-ordered)
    const float4* s4 = (const float4*)wimg;
    float4* d4 = (float4*)sWf;
    constexpr int NV = NF * 6 * 512 / 8;
    for (int i = tid; i < NV; i += 256) d4[i] = s4[i];
  }
  __syncthreads();
  const _Float16* wp = sWf + (size_t)lane * 8;

  float bias_[NF];
#pragma unroll
  for (int n2 = 0; n2 < NF; ++n2) bias_[n2] = lb[n2 * 16 + m16];

  f16x8 FA[6], FB[6];
  auto LOADA = [&](f16x8* F, int l) {        // l = local row (pos - p0)
    const _Float16* a0 = h + (size_t)sS[l] * H + kg * 8;
    const _Float16* a1 = ea + (size_t)(p0 + l) * H + kg * 8;
    const _Float16* a2 = h + (size_t)sD[l] * H + kg * 8;
    F[0] = *(const f16x8*)a0;
    F[1] = *(const f16x8*)(a0 + 32);
    F[2] = *(const f16x8*)a1;
    F[3] = *(const f16x8*)(a1 + 32);
    F[4] = *(const f16x8*)a2;
    F[5] = *(const f16x8*)(a2 + 32);
  };
  auto COMPUTE = [&](const f16x8* F, int l) {
    f32x4 acc[NF];
#pragma unroll
    for (int n2 = 0; n2 < NF; ++n2)
      acc[n2] = (f32x4){bias_[n2], bias_[n2], bias_[n2], bias_[n2]};
#pragma unroll
    for (int kk = 0; kk < 6; ++kk)
#pragma unroll
      for (int n2 = 0; n2 < NF; ++n2) {
        f16x8 bb = *(const f16x8*)(wp + ((n2 * 6 + kk) << 9));
        acc[n2] = __builtin_amdgcn_mfma_f32_16x16x32_f16(F[kk], bb, acc[n2], 0, 0, 0);
      }
    const int lbase = l - m16;
#pragma unroll
    for (int n2 = 0; n2 < NF; ++n2)
#pragma unroll
      for (int r = 0; r < 4; ++r) {
        int lr = lbase + kg * 4 + r;
        int col = n2 * 16 + m16;
        if constexpr (SCAT)
          eout[(size_t)sE[lr] * OC + col] = (OUT_T)acc[n2][r];
        else
          eout[(size_t)(p0 + lr) * OC + col] = (OUT_T)acc[n2][r];
      }
  };

  const int l0 = wv * 16 + m16;
  LOADA(FA, l0);
  if (T > 1) LOADA(FB, l0 + 64);
#pragma unroll
  for (int t = 0; t < T; ++t) {
    if (t & 1) {
      COMPUTE(FB, l0 + t * 64);
      if (t + 2 < T) LOADA(FB, l0 + (t + 2) * 64);
    } else {
      COMPUTE(FA, l0 + t * 64);
      if (t + 2 < T) LOADA(FA, l0 + (t + 2) * 64);
    }
  }
}

// ---------------- CSR build: rank (padded atomics) -> scan -> pure scatter ----------------
__global__ void k_rank(const int* __restrict__ dst, int* cntPad, int* __restrict__ rank) {
  int e = blockIdx.x * blockDim.x + threadIdx.x;
  if (e < N_EDGES)
    rank[e] = atomicAdd(&cntPad[(size_t)dst[e] * CSTRIDE], 1);
}

__global__ void k_scan_blk(const int* __restrict__ cntPad, int* __restrict__ bsum) {
  __shared__ int sh[256];
  int i = blockIdx.x * 256 + threadIdx.x;
  sh[threadIdx.x] = (i < N_NODES) ? cntPad[(size_t)i * CSTRIDE] : 0;
  __syncthreads();
  for (int s = 128; s > 0; s >>= 1) {
    if (threadIdx.x < s) sh[threadIdx.x] += sh[threadIdx.x + s];
    __syncthreads();
  }
  if (threadIdx.x == 0) bsum[blockIdx.x] = sh[0];
}

__global__ void k_scan_top(int* bsum, int nb) {  // 1 block x 512, exclusive scan
  __shared__ int sh[512];
  int t = threadIdx.x;
  int orig = (t < nb) ? bsum[t] : 0;
  sh[t] = orig;
  __syncthreads();
  for (int off = 1; off < 512; off <<= 1) {
    int v = (t >= off) ? sh[t - off] : 0;
    __syncthreads();
    sh[t] += v;
    __syncthreads();
  }
  if (t < nb) bsum[t] = sh[t] - orig;
}

__global__ void k_scan_fin(const int* __restrict__ cntPad, const int* __restrict__ bsum,
                           int* __restrict__ start, int* __restrict__ cntC) {
  __shared__ int sh[256];
  int i = blockIdx.x * 256 + threadIdx.x;
  int t = threadIdx.x;
  int orig = (i < N_NODES) ? cntPad[(size_t)i * CSTRIDE] : 0;
  sh[t] = orig;
  __syncthreads();
  for (int off = 1; off < 256; off <<= 1) {
    int v = (t >= off) ? sh[t - off] : 0;
    __syncthreads();
    sh[t] += v;
    __syncthreads();
  }
  if (i < N_NODES) {
    start[i] = bsum[blockIdx.x] + sh[t] - orig;
    cntC[i] = orig;
  }
}

__global__ void k_scatter(const int* __restrict__ src, const int* __restrict__ dst,
                          const int* __restrict__ rank, const int* __restrict__ start,
                          int4* __restrict__ eidsQ, int* __restrict__ posOf) {
  int e = blockIdx.x * blockDim.x + threadIdx.x;
  if (e < N_EDGES) {
    int d = dst[e];
    int pos = start[d] + rank[e];
    eidsQ[pos] = make_int4(e, src[e], d, 0);   // single 16B scattered store, no atomics
    posOf[e] = pos;                             // coalesced
  }
}

// ---------------- CSR softmax-aggregation: wave/node, 8 edges parallel, CONTIGUOUS ea ----------------
// block 0 also zeroes sums[256] for the following stats pass.
__global__ __launch_bounds__(256) void k_agg_csr(
    const _Float16* __restrict__ h, const _Float16* __restrict__ ea_s,
    const int4* __restrict__ eidsQ, const int* __restrict__ start,
    const int* __restrict__ cnt, _Float16* __restrict__ hsum,
    float* __restrict__ sums_clr) {
  if (blockIdx.x == 0) sums_clr[threadIdx.x] = 0.0f;
  const int lane = threadIdx.x & 63;
  const int wid  = (int)((blockIdx.x * blockDim.x + threadIdx.x) >> 6);
  if (wid >= N_NODES) return;
  const int ep = lane >> 3, fg = lane & 7;
  const int s0 = start[wid], c = cnt[wid];
  float num[8] = {0.f, 0.f, 0.f, 0.f, 0.f, 0.f, 0.f, 0.f};
  float den[8] = {0.f, 0.f, 0.f, 0.f, 0.f, 0.f, 0.f, 0.f};
  if (c > 0) {
    const int nit = (c + 7) >> 3;
    int idx = min(ep, c - 1);
    int2 pe = *(const int2*)(eidsQ + s0 + idx);   // (e, src) 8B prefix
    f16x8 hA = *(const f16x8*)(h + (size_t)pe.y * H + fg * 8);
    f16x8 eA = *(const f16x8*)(ea_s + (size_t)(s0 + idx) * H + fg * 8);
    bool vA = (ep < c);
    f16x8 hB = hA, eB = eA;
    bool vB = false;
    if (nit > 1) {
      idx = min(8 + ep, c - 1);
      pe = *(const int2*)(eidsQ + s0 + idx);
      hB = *(const f16x8*)(h + (size_t)pe.y * H + fg * 8);
      eB = *(const f16x8*)(ea_s + (size_t)(s0 + idx) * H + fg * 8);
      vB = (8 + ep < c);
    }
    for (int i = 0; i < nit; ++i) {
      f16x8 hc = hA, ec = eA;
      bool vc = vA;
      hA = hB; eA = eB; vA = vB;
      if (i + 2 < nit) {
        idx = min((i + 2) * 8 + ep, c - 1);
        pe = *(const int2*)(eidsQ + s0 + idx);
        hB = *(const f16x8*)(h + (size_t)pe.y * H + fg * 8);
        eB = *(const f16x8*)(ea_s + (size_t)(s0 + idx) * H + fg * 8);
        vB = ((i + 2) * 8 + ep < c);
      }
#pragma unroll
      for (int j = 0; j < 8; ++j) {
        float m = fmaxf((float)hc[j] + (float)ec[j], 0.0f) + EPS_GEN;
        float ex = vc ? __expf(m) : 0.0f;
        num[j] = fmaf(m, ex, num[j]);
        den[j] += ex;
      }
    }
  }
#pragma unroll
  for (int j = 0; j < 8; ++j) {
    num[j] += __shfl_xor(num[j], 8);
    num[j] += __shfl_xor(num[j], 16);
    num[j] += __shfl_xor(num[j], 32);
    den[j] += __shfl_xor(den[j], 8);
    den[j] += __shfl_xor(den[j], 16);
    den[j] += __shfl_xor(den[j], 32);
  }
  if (ep == 0) {
    f16x8 hs = *(const f16x8*)(h + (size_t)wid * H + fg * 8);
    f16x8 o;
#pragma unroll
    for (int j = 0; j < 8; ++j)
      o[j] = (_Float16)(num[j] / (den[j] + 1e-16f) + (float)hs[j]);
    *(f16x8*)(hsum + (size_t)wid * H + fg * 8) = o;
  }
}

extern "C" void kernel_launch(void* const* d_in, const int* in_sizes, int n_in,
                              void* d_out, int out_size, void* d_ws, size_t ws_size,
                              hipStream_t stream) {
  (void)in_sizes; (void)n_in; (void)out_size; (void)ws_size;
  const float* x      = (const float*)d_in[0];
  const int*   eidx   = (const int*)d_in[1];
  const float* eattr  = (const float*)d_in[2];
  const float* node_W = (const float*)d_in[3];
  const float* node_b = (const float*)d_in[4];
  const float* edge_W = (const float*)d_in[5];
  const float* edge_b = (const float*)d_in[6];
  const float* c1_W1  = (const float*)d_in[7];
  const float* c1_g   = (const float*)d_in[8];
  const float* c1_be  = (const float*)d_in[9];
  const float* c1_W2  = (const float*)d_in[10];
  const float* c2_W1  = (const float*)d_in[11];
  const float* c2_g   = (const float*)d_in[12];
  const float* c2_be  = (const float*)d_in[13];
  const float* c2_W2  = (const float*)d_in[14];
  const float* l1_W   = (const float*)d_in[15];
  const float* l1_b   = (const float*)d_in[16];
  const float* l2_W   = (const float*)d_in[17];
  const float* l2_b   = (const float*)d_in[18];

  const int* src = eidx;
  const int* dst = eidx + N_EDGES;

  char* wsb = (char*)d_ws;
  size_t off = 0;
  _Float16* ea_s  = (_Float16*)(wsb + off); off += (size_t)N_EDGES * H * 2;   // sorted-order ea
  _Float16* hA16  = (_Float16*)(wsb + off); off += (size_t)N_NODES * H * 2;
  _Float16* hB16  = (_Float16*)(wsb + off); off += (size_t)N_NODES * H * 2;
  _Float16* hC16  = (_Float16*)(wsb + off); off += (size_t)N_NODES * H * 2;
  _Float16* hsum16= (_Float16*)(wsb + off); off += (size_t)N_NODES * H * 2;
  float* sums     = (float*)(wsb + off);    off += 256 * 4;
  int* cntPad     = (int*)(wsb + off);      off += (size_t)N_NODES * CSTRIDE * 4;  // 10.24 MB
  int* startA     = (int*)(wsb + off);      off += (size_t)N_NODES * 4;
  int* cntC       = (int*)(wsb + off);      off += (size_t)N_NODES * 4;
  int* bsum       = (int*)(wsb + off);      off += 512 * 4;
  int* rankE      = (int*)(wsb + off);      off += (size_t)N_EDGES * 4;
  int4* eidsQ     = (int4*)(wsb + off);     off += (size_t)N_EDGES * 16;
  int* posOf      = (int*)(wsb + off);      off += (size_t)N_EDGES * 4;
  _Float16* wE    = (_Float16*)(wsb + off); off += DE * H * 2;
  _Float16* wN    = (_Float16*)(wsb + off); off += DN * H * 2;
  _Float16* w1a   = (_Float16*)(wsb + off); off += H * H2 * 2;
  _Float16* w1b   = (_Float16*)(wsb + off); off += H * H2 * 2;
  _Float16* w2a   = (_Float16*)(wsb + off); off += H2 * H * 2;
  _Float16* w2b   = (_Float16*)(wsb + off); off += H2 * H * 2;
  _Float16* wL1   = (_Float16*)(wsb + off); off += 3 * H * H * 2;
  _Float16* wL2   = (_Float16*)(wsb + off); off += 3 * H * 32 * 2;

  float* h_out  = (float*)d_out;                            // [N,64]
  float* ea_out = (float*)d_out + (size_t)N_NODES * H;      // [E,32]

  constexpr int NB = (N_NODES + 255) / 256;                 // 313 scan blocks

  // ---- one-time weight frag-images + cntPad zeroing (single dispatch) ----
  PrepAll P;
  P.d[0] = {edge_W, wE, DE, H, 0};       // 8 blocks
  P.d[1] = {node_W, wN, DN, H, 8};       // 32
  P.d[2] = {c1_W1, w1a, H, H2, 40};      // 32
  P.d[3] = {c2_W1, w1b, H, H2, 72};      // 32
  P.d[4] = {c1_W2, w2a, H2, H, 104};     // 32
  P.d[5] = {c2_W2, w2b, H2, H, 136};     // 32
  P.d[6] = {l1_W, wL1, 192, H, 168};     // 48
  P.d[7] = {l2_W, wL2, 192, 32, 216};    // 24 -> prep total 240
  P.zero = (float4*)cntPad;
  P.prepBlocks = 240;
  P.zeroN = (size_t)N_NODES * CSTRIDE / 4;   // 640000 float4s
  k_prep_all<<<240 + 2500, 256, 0, stream>>>(P);

  // ---- build CSR (padded-counter rank, atomic-free scatter) ----
  k_rank<<<(N_EDGES + 255) / 256, 256, 0, stream>>>(dst, cntPad, rankE);
  k_scan_blk<<<NB, 256, 0, stream>>>(cntPad, bsum);
  k_scan_top<<<1, 512, 0, stream>>>(bsum, NB);
  k_scan_fin<<<NB, 256, 0, stream>>>(cntPad, bsum, startA, cntC);
  k_scatter<<<(N_EDGES + 255) / 256, 256, 0, stream>>>(src, dst, rankE, startA, eidsQ, posOf);

  // ---- encoders (edge encoder: streaming read, scatter-write to sorted ea_s) ----
  k_dense<DE, H, false, true, false, true, false, true, false>
      <<<N_EDGES / 64, 256, 0, stream>>>(eattr, wE, edge_b,
                                         posOf, ea_s, nullptr, nullptr);
  k_dense<DN, H, false, true, false, true, false, false, false>
      <<<N_NODES / 64, 256, 0, stream>>>(x, wN, node_b,
                                         nullptr, hA16, nullptr, nullptr);

  // ---- conv layer 1 ----
  k_agg_csr<<<(N_NODES + 3) / 4, 256, 0, stream>>>(hA16, ea_s, eidsQ, startA, cntC, hsum16, sums);
  k_dense<H, H2, true, false, false, false, false, false, true>   // stats-only
      <<<N_NODES / 64, 256, 0, stream>>>(hsum16, w1a, nullptr,
                                         nullptr, nullptr, nullptr, sums);
  k_mlp2f<false><<<N_NODES / 64, 256, 0, stream>>>(hsum16, w1a, w2a, sums,
                                                   c1_g, c1_be, hB16, nullptr);
  k_edge_upd_srt<64, _Float16, 16, false>
      <<<N_EDGES / 1024, 256, 0, stream>>>(hB16, ea_s, eidsQ, wL1, l1_b, ea_s);  // in-place

  // ---- conv layer 2 ----
  k_agg_csr<<<(N_NODES + 3) / 4, 256, 0, stream>>>(hB16, ea_s, eidsQ, startA, cntC, hsum16, sums);
  k_dense<H, H2, true, false, false, false, false, false, true>   // stats-only
      <<<N_NODES / 64, 256, 0, stream>>>(hsum16, w1b, nullptr,
                                         nullptr, nullptr, nullptr, sums);
  k_mlp2f<true><<<N_NODES / 64, 256, 0, stream>>>(hsum16, w1b, w2b, sums,
                                                  c2_g, c2_be, hC16, h_out);
  k_edge_upd_srt<32, float, 16, true>
      <<<N_EDGES / 1024, 256, 0, stream>>>(hC16, ea_s, eidsQ, wL2, l2_b, ea_out);
}

// Round 16
// 590.097 us; speedup vs baseline: 1.2053x; 1.0004x over previous
//
#include <hip/hip_runtime.h>
#include <hip/hip_bf16.h>

#define N_NODES 80000
#define N_EDGES 1280000
constexpr int DN = 128;   // node input dim
constexpr int DE = 32;    // edge input dim
constexpr int H  = 64;    // hidden
constexpr int H2 = 128;   // 2*hidden
constexpr int CSTRIDE = 32;  // padded counter stride (128 B/line) to kill same-line atomic serialization
constexpr float EPS_GEN = 1e-7f;
constexpr float EPS_BN  = 1e-5f;

typedef _Float16 f16x8 __attribute__((ext_vector_type(8)));
typedef _Float16 f16x4 __attribute__((ext_vector_type(4)));
typedef float f32x4 __attribute__((ext_vector_type(4)));

__device__ __forceinline__ void atomAddF(float* p, float v) {
  __hip_atomic_fetch_add(p, v, __ATOMIC_RELAXED, __HIP_MEMORY_SCOPE_AGENT);
}

// ---------------- weight prep (all matrices) + cntPad zeroing, one dispatch ----------------
// frag-image: slab (n2*NK+kk) of 512 halves; elem ((kg*16+m16)*8+j) = W[kk*32+kg*8+j][n2*16+m16]
struct PrepDesc { const float* W; _Float16* img; int K; int OC; int blkStart; };
struct PrepAll { PrepDesc d[8]; float4* zero; int prepBlocks; size_t zeroN; };

__global__ void k_prep_all(PrepAll P) {
  int b = blockIdx.x;
  if (b >= P.prepBlocks) {   // zero cntPad region
    size_t i = (size_t)(b - P.prepBlocks) * 256 + threadIdx.x;
    if (i < P.zeroN) P.zero[i] = (float4){0.f, 0.f, 0.f, 0.f};
    return;
  }
  int i = 0;
#pragma unroll
  for (int t = 1; t < 8; ++t)
    if (P.d[t].blkStart <= b) i = t;
  const PrepDesc D = P.d[i];
  int idx = (b - D.blkStart) * 256 + threadIdx.x;
  if (idx >= D.K * D.OC) return;
  int nslabK = D.K >> 5;
  int j = idx & 7, m16 = (idx >> 3) & 15, kg = (idx >> 7) & 3;
  int slab = idx >> 9;
  int kk = slab % nslabK, n2 = slab / nslabK;
  int k = kk * 32 + kg * 8 + j, n = n2 * 16 + m16;
  D.img[idx] = (_Float16)D.W[k * D.OC + n];
}

// ---------------- generic dense MFMA: out[orow,:] = f(A[row,:]) @ W + b ----------------
// SCATOUT: orow = posmap[row]. STATS: accumulate col sums/sumsq (use with no OUT -> stats-only).
template <int K, int OC, bool IN16, bool BIAS,
          bool RELU_OUT, bool OUT16, bool OUT32, bool SCATOUT, bool STATS>
__global__ __launch_bounds__(256) void k_dense(
    const void* __restrict__ Ain, const _Float16* __restrict__ wimg,
    const float* __restrict__ bias,
    const int* __restrict__ posmap,
    _Float16* __restrict__ out16, float* __restrict__ out32,
    float* __restrict__ sums_out) {
  constexpr int NK = K / 32, NF = OC / 16;
  __shared__ float sStat[STATS ? 1024 : 1];   // [2][4 waves][128]
  const int tid = threadIdx.x, wv = tid >> 6, lane = tid & 63;
  const int m16 = lane & 15, kg = lane >> 4;
  const int rowbase = blockIdx.x * 64 + wv * 16;
  const int arow = rowbase + m16;
  f32x4 acc[NF];
#pragma unroll
  for (int n2 = 0; n2 < NF; ++n2) {
    float bv = BIAS ? bias[n2 * 16 + m16] : 0.0f;
    acc[n2] = (f32x4){bv, bv, bv, bv};
  }
  const _Float16* wp = wimg + (size_t)lane * 8;
#pragma unroll
  for (int kk = 0; kk < NK; ++kk) {
    f16x8 a;
    if constexpr (IN16) {
      const _Float16* ap = (const _Float16*)Ain + (size_t)arow * K + kg * 8 + kk * 32;
      a = *(const f16x8*)ap;
    } else {
      const float* ap = (const float*)Ain + (size_t)arow * K + kg * 8 + kk * 32;
      float4 v0 = *(const float4*)ap;
      float4 v1 = *(const float4*)(ap + 4);
      a = (f16x8){(_Float16)v0.x, (_Float16)v0.y, (_Float16)v0.z, (_Float16)v0.w,
                  (_Float16)v1.x, (_Float16)v1.y, (_Float16)v1.z, (_Float16)v1.w};
    }
#pragma unroll
    for (int n2 = 0; n2 < NF; ++n2) {
      f16x8 bb = *(const f16x8*)(wp + ((size_t)(n2 * NK + kk) << 9));
      acc[n2] = __builtin_amdgcn_mfma_f32_16x16x32_f16(a, bb, acc[n2], 0, 0, 0);
    }
  }
  if constexpr (OUT16 || OUT32) {
#pragma unroll
    for (int n2 = 0; n2 < NF; ++n2)
#pragma unroll
      for (int r = 0; r < 4; ++r) {
        float o = acc[n2][r];
        if constexpr (RELU_OUT) o = fmaxf(o, 0.0f);
        int orow = rowbase + kg * 4 + r;
        if constexpr (SCATOUT) orow = posmap[orow];
        size_t oi = (size_t)orow * OC + n2 * 16 + m16;
        if constexpr (OUT16) out16[oi] = (_Float16)o;
        if constexpr (OUT32) out32[oi] = o;
      }
  }
  if constexpr (STATS) {
    static_assert(!STATS || NF == 8, "STATS assumes OC==128");
#pragma unroll
    for (int n2 = 0; n2 < NF; ++n2) {
      float s = acc[n2][0] + acc[n2][1] + acc[n2][2] + acc[n2][3];
      float q = acc[n2][0] * acc[n2][0] + acc[n2][1] * acc[n2][1] +
                acc[n2][2] * acc[n2][2] + acc[n2][3] * acc[n2][3];
      s += __shfl_xor(s, 16); s += __shfl_xor(s, 32);
      q += __shfl_xor(q, 16); q += __shfl_xor(q, 32);
      if (kg == 0) {
        sStat[wv * 128 + n2 * 16 + m16] = s;
        sStat[512 + wv * 128 + n2 * 16 + m16] = q;
      }
    }
    __syncthreads();
    {
      int which = tid >> 7, f = tid & 127;
      const float* b0 = sStat + which * 512;
      float v = b0[f] + b0[128 + f] + b0[256 + f] + b0[384 + f];
      atomAddF(&sums_out[which * H2 + f], v);
    }
  }
}

// ---------------- fused BN-MLP: out = relu( relu(bn(hsum@W1)) @ W2 ) ----------------
template <bool OUT32>
__global__ __launch_bounds__(256) void k_mlp2f(
    const _Float16* __restrict__ hsum, const _Float16* __restrict__ w1img,
    const _Float16* __restrict__ w2img, const float* __restrict__ sums,
    const float* __restrict__ g, const float* __restrict__ be,
    _Float16* __restrict__ out16, float* __restrict__ out32) {
  constexpr int TP = 136;                 // LDS tile pitch (halves)
  __shared__ float sSC[H2], sSH[H2];
  __shared__ _Float16 sT[64 * TP];        // 17408 B
  const int tid = threadIdx.x, wv = tid >> 6, lane = tid & 63;
  const int m16 = lane & 15, kg = lane >> 4;
  const int rowbase = blockIdx.x * 64 + wv * 16;

  for (int i = tid; i < H2; i += 256) {
    float mu  = sums[i] * (1.0f / N_NODES);
    float var = sums[H2 + i] * (1.0f / N_NODES) - mu * mu;
    float sc  = rsqrtf(var + EPS_BN) * g[i];
    sSC[i] = sc;
    sSH[i] = be[i] - mu * sc;
  }

  // phase 1: h3 = hsum @ W1 (K=64 -> NK=2, OC=128 -> NF=8)
  f32x4 acc1[8];
#pragma unroll
  for (int n2 = 0; n2 < 8; ++n2) acc1[n2] = (f32x4){0.f, 0.f, 0.f, 0.f};
  const _Float16* wp1 = w1img + (size_t)lane * 8;
#pragma unroll
  for (int kk = 0; kk < 2; ++kk) {
    f16x8 a = *(const f16x8*)(hsum + (size_t)(rowbase + m16) * H + kg * 8 + kk * 32);
#pragma unroll
    for (int n2 = 0; n2 < 8; ++n2) {
      f16x8 bb = *(const f16x8*)(wp1 + ((size_t)(n2 * 2 + kk) << 9));
      acc1[n2] = __builtin_amdgcn_mfma_f32_16x16x32_f16(a, bb, acc1[n2], 0, 0, 0);
    }
  }
  __syncthreads();   // sSC/sSH ready
  // phase 2: BN affine + relu on D-layout, write LDS transpose tile
#pragma unroll
  for (int n2 = 0; n2 < 8; ++n2) {
    int col = n2 * 16 + m16;
    float sc = sSC[col], sh = sSH[col];
#pragma unroll
    for (int r = 0; r < 4; ++r) {
      float v = fmaxf(fmaf(acc1[n2][r], sc, sh), 0.0f);
      sT[(wv * 16 + kg * 4 + r) * TP + col] = (_Float16)v;
    }
  }
  __syncthreads();
  // phase 3: out = sT @ W2 (K=128 -> NK=4, OC=64 -> NF=4)
  f32x4 acc2[4];
#pragma unroll
  for (int n2 = 0; n2 < 4; ++n2) acc2[n2] = (f32x4){0.f, 0.f, 0.f, 0.f};
  const _Float16* wp2 = w2img + (size_t)lane * 8;
#pragma unroll
  for (int kk = 0; kk < 4; ++kk) {
    f16x8 a2 = *(const f16x8*)&sT[(wv * 16 + m16) * TP + kg * 8 + kk * 32];
#pragma unroll
    for (int n2 = 0; n2 < 4; ++n2) {
      f16x8 bb = *(const f16x8*)(wp2 + ((size_t)(n2 * 4 + kk) << 9));
      acc2[n2] = __builtin_amdgcn_mfma_f32_16x16x32_f16(a2, bb, acc2[n2], 0, 0, 0);
    }
  }
#pragma unroll
  for (int n2 = 0; n2 < 4; ++n2)
#pragma unroll
    for (int r = 0; r < 4; ++r) {
      float o = fmaxf(acc2[n2][r], 0.0f);
      size_t oi = (size_t)(rowbase + kg * 4 + r) * H + n2 * 16 + m16;
      out16[oi] = (_Float16)o;
      if constexpr (OUT32) out32[oi] = o;
    }
}

// ---------------- edge update on sorted positions: T tiles/block ----------------
template <int OC, typename OUT_T, int T, bool SCAT>
__global__ __launch_bounds__(256) void k_edge_upd_srt(
    const _Float16* __restrict__ h, const _Float16* __restrict__ ea,
    const int4* __restrict__ eidsQ,
    const _Float16* __restrict__ wimg, const float* __restrict__ lb,
    OUT_T* __restrict__ eout) {
  constexpr int NF = OC / 16;
  __shared__ _Float16 sWf[NF * 6 * 512];
  __shared__ int sS[T * 64], sD[T * 64];
  __shared__ int sE[SCAT ? T * 64 : 1];
  const int tid = threadIdx.x, wv = tid >> 6, lane = tid & 63;
  const int m16 = lane & 15, kg = lane >> 4;
  const int p0 = blockIdx.x * (T * 64);

  for (int i = tid; i < T * 64; i += 256) {
    int4 t = eidsQ[p0 + i];
    sS[i] = t.y;
    sD[i] = t.z;
    if constexpr (SCAT) sE[i] = t.x;
  }
  {  // stage weights: linear copy (frag-ordered)
    const float4* s4 = (const float4*)wimg;
    float4* d4 = (float4*)sWf;
    constexpr int NV = NF * 6 * 512 / 8;
    for (int i = tid; i < NV; i += 256) d4[i] = s4[i];
  }
  __syncthreads();
  const _Float16* wp = sWf + (size_t)lane * 8;

  float bias_[NF];
#pragma unroll
  for (int n2 = 0; n2 < NF; ++n2) bias_[n2] = lb[n2 * 16 + m16];

  f16x8 FA[6], FB[6];
  auto LOADA = [&](f16x8* F, int l) {        // l = local row (pos - p0)
    const _Float16* a0 = h + (size_t)sS[l] * H + kg * 8;
    const _Float16* a1 = ea + (size_t)(p0 + l) * H + kg * 8;
    const _Float16* a2 = h + (size_t)sD[l] * H + kg * 8;
    F[0] = *(const f16x8*)a0;
    F[1] = *(const f16x8*)(a0 + 32);
    F[2] = *(const f16x8*)a1;
    F[3] = *(const f16x8*)(a1 + 32);
    F[4] = *(const f16x8*)a2;
    F[5] = *(const f16x8*)(a2 + 32);
  };
  auto COMPUTE = [&](const f16x8* F, int l) {
    f32x4 acc[NF];
#pragma unroll
    for (int n2 = 0; n2 < NF; ++n2)
      acc[n2] = (f32x4){bias_[n2], bias_[n2], bias_[n2], bias_[n2]};
#pragma unroll
    for (int kk = 0; kk < 6; ++kk)
#pragma unroll
      for (int n2 = 0; n2 < NF; ++n2) {
        f16x8 bb = *(const f16x8*)(wp + ((n2 * 6 + kk) << 9));
        acc[n2] = __builtin_amdgcn_mfma_f32_16x16x32_f16(F[kk], bb, acc[n2], 0, 0, 0);
      }
    const int lbase = l - m16;
#pragma unroll
    for (int n2 = 0; n2 < NF; ++n2)
#pragma unroll
      for (int r = 0; r < 4; ++r) {
        int lr = lbase + kg * 4 + r;
        int col = n2 * 16 + m16;
        if constexpr (SCAT)
          eout[(size_t)sE[lr] * OC + col] = (OUT_T)acc[n2][r];
        else
          eout[(size_t)(p0 + lr) * OC + col] = (OUT_T)acc[n2][r];
      }
  };

  const int l0 = wv * 16 + m16;
  LOADA(FA, l0);
  if (T > 1) LOADA(FB, l0 + 64);
#pragma unroll
  for (int t = 0; t < T; ++t) {
    if (t & 1) {
      COMPUTE(FB, l0 + t * 64);
      if (t + 2 < T) LOADA(FB, l0 + (t + 2) * 64);
    } else {
      COMPUTE(FA, l0 + t * 64);
      if (t + 2 < T) LOADA(FA, l0 + (t + 2) * 64);
    }
  }
}

// ---------------- CSR build: rank (padded atomics) -> scan -> pure scatter ----------------
__global__ void k_rank(const int* __restrict__ dst, int* cntPad, int* __restrict__ rank) {
  int e = blockIdx.x * blockDim.x + threadIdx.x;
  if (e < N_EDGES)
    rank[e] = atomicAdd(&cntPad[(size_t)dst[e] * CSTRIDE], 1);
}

__global__ void k_scan_blk(const int* __restrict__ cntPad, int* __restrict__ bsum) {
  __shared__ int sh[256];
  int i = blockIdx.x * 256 + threadIdx.x;
  sh[threadIdx.x] = (i < N_NODES) ? cntPad[(size_t)i * CSTRIDE] : 0;
  __syncthreads();
  for (int s = 128; s > 0; s >>= 1) {
    if (threadIdx.x < s) sh[threadIdx.x] += sh[threadIdx.x + s];
    __syncthreads();
  }
  if (threadIdx.x == 0) bsum[blockIdx.x] = sh[0];
}

__global__ void k_scan_top(int* bsum, int nb) {  // 1 block x 512, exclusive scan
  __shared__ int sh[512];
  int t = threadIdx.x;
  int orig = (t < nb) ? bsum[t] : 0;
  sh[t] = orig;
  __syncthreads();
  for (int off = 1; off < 512; off <<= 1) {
    int v = (t >= off) ? sh[t - off] : 0;
    __syncthreads();
    sh[t] += v;
    __syncthreads();
  }
  if (t < nb) bsum[t] = sh[t] - orig;
}

__global__ void k_scan_fin(const int* __restrict__ cntPad, const int* __restrict__ bsum,
                           int* __restrict__ start, int* __restrict__ cntC) {
  __shared__ int sh[256];
  int i = blockIdx.x * 256 + threadIdx.x;
  int t = threadIdx.x;
  int orig = (i < N_NODES) ? cntPad[(size_t)i * CSTRIDE] : 0;
  sh[t] = orig;
  __syncthreads();
  for (int off = 1; off < 256; off <<= 1) {
    int v = (t >= off) ? sh[t - off] : 0;
    __syncthreads();
    sh[t] += v;
    __syncthreads();
  }
  if (i < N_NODES) {
    start[i] = bsum[blockIdx.x] + sh[t] - orig;
    cntC[i] = orig;
  }
}

__global__ void k_scatter(const int* __restrict__ src, const int* __restrict__ dst,
                          const int* __restrict__ rank, const int* __restrict__ start,
                          int4* __restrict__ eidsQ, int* __restrict__ posOf) {
  int e = blockIdx.x * blockDim.x + threadIdx.x;
  if (e < N_EDGES) {
    int d = dst[e];
    int pos = start[d] + rank[e];
    eidsQ[pos] = make_int4(e, src[e], d, 0);   // single 16B scattered store, no atomics
    posOf[e] = pos;                             // coalesced
  }
}

// ---------------- CSR softmax-aggregation: wave/node, 8 edges parallel, CONTIGUOUS ea ----------------
// block 0 also zeroes sums[256] for the following stats pass.
__global__ __launch_bounds__(256) void k_agg_csr(
    const _Float16* __restrict__ h, const _Float16* __restrict__ ea_s,
    const int4* __restrict__ eidsQ, const int* __restrict__ start,
    const int* __restrict__ cnt, _Float16* __restrict__ hsum,
    float* __restrict__ sums_clr) {
  if (blockIdx.x == 0) sums_clr[threadIdx.x] = 0.0f;
  const int lane = threadIdx.x & 63;
  const int wid  = (int)((blockIdx.x * blockDim.x + threadIdx.x) >> 6);
  if (wid >= N_NODES) return;
  const int ep = lane >> 3, fg = lane & 7;
  const int s0 = start[wid], c = cnt[wid];
  float num[8] = {0.f, 0.f, 0.f, 0.f, 0.f, 0.f, 0.f, 0.f};
  float den[8] = {0.f, 0.f, 0.f, 0.f, 0.f, 0.f, 0.f, 0.f};
  if (c > 0) {
    const int nit = (c + 7) >> 3;
    int idx = min(ep, c - 1);
    int2 pe = *(const int2*)(eidsQ + s0 + idx);   // (e, src) 8B prefix
    f16x8 hA = *(const f16x8*)(h + (size_t)pe.y * H + fg * 8);
    f16x8 eA = *(const f16x8*)(ea_s + (size_t)(s0 + idx) * H + fg * 8);
    bool vA = (ep < c);
    f16x8 hB = hA, eB = eA;
    bool vB = false;
    if (nit > 1) {
      idx = min(8 + ep, c - 1);
      pe = *(const int2*)(eidsQ + s0 + idx);
      hB = *(const f16x8*)(h + (size_t)pe.y * H + fg * 8);
      eB = *(const f16x8*)(ea_s + (size_t)(s0 + idx) * H + fg * 8);
      vB = (8 + ep < c);
    }
    for (int i = 0; i < nit; ++i) {
      f16x8 hc = hA, ec = eA;
      bool vc = vA;
      hA = hB; eA = eB; vA = vB;
      if (i + 2 < nit) {
        idx = min((i + 2) * 8 + ep, c - 1);
        pe = *(const int2*)(eidsQ + s0 + idx);
        hB = *(const f16x8*)(h + (size_t)pe.y * H + fg * 8);
        eB = *(const f16x8*)(ea_s + (size_t)(s0 + idx) * H + fg * 8);
        vB = ((i + 2) * 8 + ep < c);
      }
#pragma unroll
      for (int j = 0; j < 8; ++j) {
        float m = fmaxf((float)hc[j] + (float)ec[j], 0.0f) + EPS_GEN;
        float ex = vc ? __expf(m) : 0.0f;
        num[j] = fmaf(m, ex, num[j]);
        den[j] += ex;
      }
    }
  }
#pragma unroll
  for (int j = 0; j < 8; ++j) {
    num[j] += __shfl_xor(num[j], 8);
    num[j] += __shfl_xor(num[j], 16);
    num[j] += __shfl_xor(num[j], 32);
    den[j] += __shfl_xor(den[j], 8);
    den[j] += __shfl_xor(den[j], 16);
    den[j] += __shfl_xor(den[j], 32);
  }
  if (ep == 0) {
    f16x8 hs = *(const f16x8*)(h + (size_t)wid * H + fg * 8);
    f16x8 o;
#pragma unroll
    for (int j = 0; j < 8; ++j)
      o[j] = (_Float16)(num[j] / (den[j] + 1e-16f) + (float)hs[j]);
    *(f16x8*)(hsum + (size_t)wid * H + fg * 8) = o;
  }
}

extern "C" void kernel_launch(void* const* d_in, const int* in_sizes, int n_in,
                              void* d_out, int out_size, void* d_ws, size_t ws_size,
                              hipStream_t stream) {
  (void)in_sizes; (void)n_in; (void)out_size; (void)ws_size;
  const float* x      = (const float*)d_in[0];
  const int*   eidx   = (const int*)d_in[1];
  const float* eattr  = (const float*)d_in[2];
  const float* node_W = (const float*)d_in[3];
  const float* node_b = (const float*)d_in[4];
  const float* edge_W = (const float*)d_in[5];
  const float* edge_b = (const float*)d_in[6];
  const float* c1_W1  = (const float*)d_in[7];
  const float* c1_g   = (const float*)d_in[8];
  const float* c1_be  = (const float*)d_in[9];
  const float* c1_W2  = (const float*)d_in[10];
  const float* c2_W1  = (const float*)d_in[11];
  const float* c2_g   = (const float*)d_in[12];
  const float* c2_be  = (const float*)d_in[13];
  const float* c2_W2  = (const float*)d_in[14];
  const float* l1_W   = (const float*)d_in[15];
  const float* l1_b   = (const float*)d_in[16];
  const float* l2_W   = (const float*)d_in[17];
  const float* l2_b   = (const float*)d_in[18];

  const int* src = eidx;
  const int* dst = eidx + N_EDGES;

  char* wsb = (char*)d_ws;
  size_t off = 0;
  _Float16* ea_s  = (_Float16*)(wsb + off); off += (size_t)N_EDGES * H * 2;   // sorted-order ea
  _Float16* hA16  = (_Float16*)(wsb + off); off += (size_t)N_NODES * H * 2;
  _Float16* hB16  = (_Float16*)(wsb + off); off += (size_t)N_NODES * H * 2;
  _Float16* hC16  = (_Float16*)(wsb + off); off += (size_t)N_NODES * H * 2;
  _Float16* hsum16= (_Float16*)(wsb + off); off += (size_t)N_NODES * H * 2;
  float* sums     = (float*)(wsb + off);    off += 256 * 4;
  int* cntPad     = (int*)(wsb + off);      off += (size_t)N_NODES * CSTRIDE * 4;  // 10.24 MB
  int* startA     = (int*)(wsb + off);      off += (size_t)N_NODES * 4;
  int* cntC       = (int*)(wsb + off);      off += (size_t)N_NODES * 4;
  int* bsum       = (int*)(wsb + off);      off += 512 * 4;
  int* rankE      = (int*)(wsb + off);      off += (size_t)N_EDGES * 4;
  int4* eidsQ     = (int4*)(wsb + off);     off += (size_t)N_EDGES * 16;
  int* posOf      = (int*)(wsb + off);      off += (size_t)N_EDGES * 4;
  _Float16* wE    = (_Float16*)(wsb + off); off += DE * H * 2;
  _Float16* wN    = (_Float16*)(wsb + off); off += DN * H * 2;
  _Float16* w1a   = (_Float16*)(wsb + off); off += H * H2 * 2;
  _Float16* w1b   = (_Float16*)(wsb + off); off += H * H2 * 2;
  _Float16* w2a   = (_Float16*)(wsb + off); off += H2 * H * 2;
  _Float16* w2b   = (_Float16*)(wsb + off); off += H2 * H * 2;
  _Float16* wL1   = (_Float16*)(wsb + off); off += 3 * H * H * 2;
  _Float16* wL2   = (_Float16*)(wsb + off); off += 3 * H * 32 * 2;

  float* h_out  = (float*)d_out;                            // [N,64]
  float* ea_out = (float*)d_out + (size_t)N_NODES * H;      // [E,32]

  constexpr int NB = (N_NODES + 255) / 256;                 // 313 scan blocks

  // ---- one-time weight frag-images + cntPad zeroing (single dispatch) ----
  PrepAll P;
  P.d[0] = {edge_W, wE, DE, H, 0};       // 8 blocks
  P.d[1] = {node_W, wN, DN, H, 8};       // 32
  P.d[2] = {c1_W1, w1a, H, H2, 40};      // 32
  P.d[3] = {c2_W1, w1b, H, H2, 72};      // 32
  P.d[4] = {c1_W2, w2a, H2, H, 104};     // 32
  P.d[5] = {c2_W2, w2b, H2, H, 136};     // 32
  P.d[6] = {l1_W, wL1, 192, H, 168};     // 48
  P.d[7] = {l2_W, wL2, 192, 32, 216};    // 24 -> prep total 240
  P.zero = (float4*)cntPad;
  P.prepBlocks = 240;
  P.zeroN = (size_t)N_NODES * CSTRIDE / 4;   // 640000 float4s
  k_prep_all<<<240 + 2500, 256, 0, stream>>>(P);

  // ---- build CSR (padded-counter rank, atomic-free scatter) ----
  k_rank<<<(N_EDGES + 255) / 256, 256, 0, stream>>>(dst, cntPad, rankE);
  k_scan_blk<<<NB, 256, 0, stream>>>(cntPad, bsum);
  k_scan_top<<<1, 512, 0, stream>>>(bsum, NB);
  k_scan_fin<<<NB, 256, 0, stream>>>(cntPad, bsum, startA, cntC);
  k_scatter<<<(N_EDGES + 255) / 256, 256, 0, stream>>>(src, dst, rankE, startA, eidsQ, posOf);

  // ---- encoders (edge encoder: streaming read, scatter-write to sorted ea_s) ----
  k_dense<DE, H, false, true, false, true, false, true, false>
      <<<N_EDGES / 64, 256, 0, stream>>>(eattr, wE, edge_b,
                                         posOf, ea_s, nullptr, nullptr);
  k_dense<DN, H, false, true, false, true, false, false, false>
      <<<N_NODES / 64, 256, 0, stream>>>(x, wN, node_b,
                                         nullptr, hA16, nullptr, nullptr);

  // ---- conv layer 1 ----
  k_agg_csr<<<(N_NODES + 3) / 4, 256, 0, stream>>>(hA16, ea_s, eidsQ, startA, cntC, hsum16, sums);
  k_dense<H, H2, true, false, false, false, false, false, true>   // stats-only
      <<<N_NODES / 64, 256, 0, stream>>>(hsum16, w1a, nullptr,
                                         nullptr, nullptr, nullptr, sums);
  k_mlp2f<false><<<N_NODES / 64, 256, 0, stream>>>(hsum16, w1a, w2a, sums,
                                                   c1_g, c1_be, hB16, nullptr);
  k_edge_upd_srt<64, _Float16, 16, false>
      <<<N_EDGES / 1024, 256, 0, stream>>>(hB16, ea_s, eidsQ, wL1, l1_b, ea_s);  // in-place

  // ---- conv layer 2 ----
  k_agg_csr<<<(N_NODES + 3) / 4, 256, 0, stream>>>(hB16, ea_s, eidsQ, startA, cntC, hsum16, sums);
  k_dense<H, H2, true, false, false, false, false, false, true>   // stats-only
      <<<N_NODES / 64, 256, 0, stream>>>(hsum16, w1b, nullptr,
                                         nullptr, nullptr, nullptr, sums);
  k_mlp2f<true><<<N_NODES / 64, 256, 0, stream>>>(hsum16, w1b, w2b, sums,
                                                  c2_g, c2_be, hC16, h_out);
  k_edge_upd_srt<32, float, 16, true>
      <<<N_EDGES / 1024, 256, 0, stream>>>(hC16, ea_s, eidsQ, wL2, l2_b, ea_out);
}